// Round 8
// baseline (311.352 us; speedup 1.0000x reference)
//
#include <hip/hip_runtime.h>

// Problem constants
#define B 8
#define N 4096
#define C 128
#define C2 256          // K-dim of fused GEMM: [ptl | s]
#define KNN 21          // top-(K+1), drop nearest
#define CAP 22          // per-lane append buffer capacity (slots 0..21)

typedef unsigned long long u64;
typedef unsigned int u32;
typedef unsigned short u16;

typedef __attribute__((ext_vector_type(8))) short bf16x8;
typedef __attribute__((ext_vector_type(4))) float f32x4;

__device__ __forceinline__ float bf2f(u16 u) {
    return __uint_as_float(((u32)u) << 16);
}
__device__ __forceinline__ u16 f2bf(float f) {  // round-to-nearest-even
    u32 x = __float_as_uint(f);
    return (u16)((x + 0x7FFFu + ((x >> 16) & 1u)) >> 16);
}

// ---------------------------------------------------------------------------
// K1: transpose + leaky_relu: points (B,C,N) f32 -> X[b][n][c] (c<128) bf16.
// Also prepacks cand[b][m] = float4(x, y, z, sq_norm) once per point (same
// __fmul_rn/__fadd_rn sequence the KNN staging used inline -> bit-identical).
// ---------------------------------------------------------------------------
__global__ __launch_bounds__(256) void k_transpose_lrelu(
        const float* __restrict__ pts, u16* __restrict__ X,
        const float* __restrict__ xyz, float4* __restrict__ cand) {
    __shared__ u16 tile[32][33];
    int b  = blockIdx.z;
    int c0 = blockIdx.y * 32;
    int n0 = blockIdx.x * 32;
    int tx = threadIdx.x, ty = threadIdx.y;   // 32 x 8

    if (blockIdx.y == 0 && ty == 0) {         // prepack: 32 lanes, 32 points
        int n = n0 + tx;
        const float* xz = xyz + (size_t)b * 3 * N;
        float x = xz[n], y = xz[N + n], z = xz[2 * N + n];
        float sn = __fadd_rn(__fadd_rn(__fmul_rn(x, x), __fmul_rn(y, y)),
                             __fmul_rn(z, z));
        cand[(size_t)b * N + n] = make_float4(x, y, z, sn);
    }

    const float* src = pts + (size_t)b * C * N;
    #pragma unroll
    for (int i = 0; i < 32; i += 8) {
        float v = src[(size_t)(c0 + ty + i) * N + n0 + tx];
        if (v < 0.f) v = __fmul_rn(v, 0.01f);
        tile[ty + i][tx] = f2bf(v);
    }
    __syncthreads();
    u16* dst = X + (size_t)b * N * C2;
    #pragma unroll
    for (int i = 0; i < 32; i += 8) {
        dst[(size_t)(n0 + ty + i) * C2 + (c0 + tx)] = tile[tx][ty + i];
    }
}

// ---------------------------------------------------------------------------
// K2: exact KNN (top-21 by (sq, idx), drop min) + neighbor-feature gather-sum.
// Scan loop BYTE-FOR-BYTE r3 (u32 sortable keys -- f32 keys cost +55us stall,
// measured 2x; smin shared-threshold removed -- r7 proved null: insertions
// are ~72% front-loaded in sc=0 where sthr is still inf).
// ONE delta vs r3: EARLY-EXIT BUBBLE in compact. A single inserted element
// bubbles up only until it settles; once sw=false for a lane every later
// step is a no-op (prefix property). Check __ballot(sw) before each exchange
// and break when no lane swaps. Steady-state slots (1-3 inserting lanes,
// E[max depth] ~10-16 of 20) skip ~half the 5-VALU steps; the check itself
// is 1 v_cmp + scalar-pipe ops (co-issued, ~0 VALU). Bit-exact: skipped
// steps are provably no-ops for all lanes; strict-compare ties untouched.
// ---------------------------------------------------------------------------
__global__ __launch_bounds__(256) void k_knn_gather(
        const float4* __restrict__ cand, u16* __restrict__ X) {
    __shared__ __align__(16) char lds[52224];
    float4* stg  = (float4*)lds;                      // [4][288]  18432 B
    u32*    kbuf = (u32*)(lds + 18432);               // [CAP][256] 22528 B
    u16*    ibuf = (u16*)(lds + 18432 + 22528);       // [CAP][256] 11264 B
    u64*    mg   = (u64*)lds;                         // [256][21]  43008 B (phase B)
    __shared__ u16 win[64 * KNN];

    int tid = threadIdx.x;
    int w = tid >> 6, l = tid & 63;
    int b = blockIdx.y;
    int n0 = blockIdx.x * 64;
    int nq = n0 + l;

    const float4* candb = cand + (size_t)b * N;
    float4 cq = candb[nq];                            // query point (coalesced)
    float qx = cq.x, qy = cq.y, qz = cq.z, snq = cq.w;

    u32 key[KNN], idx[KNN];
    #pragma unroll
    for (int i = 0; i < KNN; ++i) { key[i] = 0xFFFFFFFFu; idx[i] = 0u; }
    int cnt = 0;
    u32 thr = 0xFFFFFFFFu;

    auto compact = [&]() {
        #pragma unroll 1
        for (int i = 0; i < CAP; ++i) {
            if (__ballot(i < cnt) == 0ull) break;
            u32 kv = kbuf[i * 256 + tid];
            u32 iv = ibuf[i * 256 + tid];
            bool ins = (i < cnt) && (kv < key[20]);   // strict: ties keep old
            if (__ballot(ins) != 0ull) {
                key[20] = ins ? kv : key[20];
                idx[20] = ins ? iv : idx[20];
                #pragma unroll
                for (int t = 19; t >= 0; --t) {       // stable bubble (strict >)
                    bool sw = key[t] > key[t + 1];
                    if (__ballot(sw) == 0ull) break;  // all lanes settled
                    u32 ka = sw ? key[t + 1] : key[t];
                    u32 kz = sw ? key[t] : key[t + 1];
                    u32 ia = sw ? idx[t + 1] : idx[t];
                    u32 iz = sw ? idx[t] : idx[t + 1];
                    key[t] = ka; key[t + 1] = kz;
                    idx[t] = ia; idx[t + 1] = iz;
                }
            }
        }
        cnt = 0;
        thr = key[20];
    };

    float4* mystg = stg + w * 288;
    int wl = l + (l >> 3);                            // padded staging index

    for (int sc = 0; sc < 4; ++sc) {
        int m0 = w * 1024 + sc * 256;
        // stage 256 candidates from prepacked cand (coalesced float4)
        float4 v0 = candb[m0 + l];
        float4 v1 = candb[m0 + l + 64];
        float4 v2 = candb[m0 + l + 128];
        float4 v3 = candb[m0 + l + 192];
        mystg[wl]       = v0;                         // conflict-free writes
        mystg[wl + 72]  = v1;
        mystg[wl + 144] = v2;
        mystg[wl + 216] = v3;
        asm volatile("s_waitcnt lgkmcnt(0)" ::: "memory");
        for (int cc = 0; cc < 256; cc += 8) {
            int base = cc + (cc >> 3);                // wave-uniform padded base
            #pragma unroll
            for (int j = 0; j < 8; ++j) {
                float4 cp = mystg[base + j];          // wave-broadcast read
                int m = m0 + cc + j;
                float dot = __fadd_rn(__fadd_rn(__fmul_rn(qx, cp.x),
                                                __fmul_rn(qy, cp.y)),
                                      __fmul_rn(qz, cp.z));
                float sq = __fadd_rn(__fsub_rn(snq, __fadd_rn(dot, dot)), cp.w);
                u32 bits = __float_as_uint(sq);
                u32 kb = bits ^ (0x80000000u | (u32)(((int)bits) >> 31));
                kbuf[cnt * 256 + tid] = kb;           // unconditional append
                ibuf[cnt * 256 + tid] = (u16)m;
                cnt += (kb < thr);                    // strict: ties dropped
            }
            if (__ballot(cnt >= 15) != 0ull) compact();
        }
    }
    compact();

    __syncthreads();                                  // phase-A buffers dead
    #pragma unroll
    for (int j = 0; j < KNN; ++j)
        mg[(w * 64 + l) * KNN + j] = ((u64)key[j] << 32) | (u64)idx[j];
    __syncthreads();

    if (w == 0) {                                     // 4-way merge per query
        int p0 = 0, p1 = 0, p2 = 0, p3 = 0;
        for (int j = 0; j < KNN; ++j) {
            u64 c0 = mg[(0 * 64 + l) * KNN + p0];
            u64 c1 = mg[(1 * 64 + l) * KNN + p1];
            u64 c2 = mg[(2 * 64 + l) * KNN + p2];
            u64 c3 = mg[(3 * 64 + l) * KNN + p3];
            u64 m01 = c0 < c1 ? c0 : c1; int s01 = c0 < c1 ? 0 : 1;
            u64 m23 = c2 < c3 ? c2 : c3; int s23 = c2 < c3 ? 2 : 3;
            u64 mm = m01 < m23 ? m01 : m23;
            int sel = m01 < m23 ? s01 : s23;
            win[l * KNN + j] = (u16)(mm & 0xFFFFu);
            p0 += (sel == 0); p1 += (sel == 1); p2 += (sel == 2); p3 += (sel == 3);
        }
    }
    __syncthreads();

    // gather-sum: wave w handles 16 queries; lane covers channels 2l, 2l+1
    const u16* Xb = X + (size_t)b * N * C2;
    for (int qq = 0; qq < 16; ++qq) {
        int q = w * 16 + qq;
        float f0 = 0.f, f1 = 0.f;
        #pragma unroll
        for (int j = 1; j < KNN; ++j) {               // skip nearest (j=0)
            int m = win[q * KNN + j];
            u32 u2 = *(const u32*)(Xb + (size_t)m * C2 + 2 * l);
            f0 += bf2f((u16)(u2 & 0xFFFFu));
            f1 += bf2f((u16)(u2 >> 16));
        }
        u16* dst = X + ((size_t)b * N + n0 + q) * C2 + 128 + 2 * l;
        *(u32*)dst = ((u32)f2bf(f1) << 16) | (u32)f2bf(f0);
    }
}

// ---------------------------------------------------------------------------
// K3: MFMA GEMM. out[b][o][n] = (W[o][:].X[b][n][:] + bc[o]+20bg[o])/21 + pts.
// One block per (b, 64-row n-panel), grid 512. The 64x256 bf16 X panel (32KB)
// staged ONCE, coalesced, into LDS (row pad 264 u16 = 528B: 16B-aligned, bank
// stride 132 -> 2-way = free). 4 waves x 2 o-tiles each; B-frags ds_read_b128
// shared across the o-pair. Identical MFMA math / rounding / output map.
// C/D map: col=lane&15 (n), row=(lane>>4)*4+reg (o)  [m89-verified]
// ---------------------------------------------------------------------------
__global__ __launch_bounds__(256) void k_gemm_mfma(
        const u16* __restrict__ X, const float* __restrict__ Wc,
        const float* __restrict__ Wg, const float* __restrict__ pts,
        const float* __restrict__ bc, const float* __restrict__ bg,
        float* __restrict__ out) {
    __shared__ u16 xs[64][264];                       // 33792 B, padded rows
    int bid = blockIdx.x;                             // 0..511
    int b  = bid >> 6;
    int n0 = (bid & 63) * 64;
    int tid = threadIdx.x;

    const u16* Xb = X + (size_t)b * N * C2;
    #pragma unroll
    for (int it = 0; it < 8; ++it) {                  // stage panel, coalesced
        int t = it * 256 + tid;                       // 0..2047
        int r = t >> 5, cch = t & 31;                 // row, 16B chunk
        *(bf16x8*)(&xs[r][cch * 8]) =
            *(const bf16x8*)(Xb + (size_t)(n0 + r) * C2 + cch * 8);
    }
    __syncthreads();

    int w = tid >> 6, lane = tid & 63;
    int l16 = lane & 15, lq = lane >> 4;
    // wave w handles o-tiles 2w, 2w+1 (o rows w*32 .. w*32+31)
    const float* wc0 = Wc + (size_t)(w * 32 + l16) * 128 + lq * 8;
    const float* wc1 = Wc + (size_t)(w * 32 + 16 + l16) * 128 + lq * 8;
    const float* wg0 = Wg + (size_t)(w * 32 + l16) * 128 + lq * 8;
    const float* wg1 = Wg + (size_t)(w * 32 + 16 + l16) * 128 + lq * 8;

    f32x4 acc[2][4];
    #pragma unroll
    for (int oo = 0; oo < 2; ++oo)
        #pragma unroll
        for (int t = 0; t < 4; ++t)
            acc[oo][t] = (f32x4){0.f, 0.f, 0.f, 0.f};

    #pragma unroll
    for (int kk = 0; kk < 8; ++kk) {
        const float* s0 = (kk < 4) ? (wc0 + kk * 32) : (wg0 + (kk - 4) * 32);
        const float* s1 = (kk < 4) ? (wc1 + kk * 32) : (wg1 + (kk - 4) * 32);
        float4 wa0 = *(const float4*)s0, wb0 = *(const float4*)(s0 + 4);
        float4 wa1 = *(const float4*)s1, wb1 = *(const float4*)(s1 + 4);
        bf16x8 a0, a1;
        a0[0] = (short)f2bf(wa0.x); a0[1] = (short)f2bf(wa0.y);
        a0[2] = (short)f2bf(wa0.z); a0[3] = (short)f2bf(wa0.w);
        a0[4] = (short)f2bf(wb0.x); a0[5] = (short)f2bf(wb0.y);
        a0[6] = (short)f2bf(wb0.z); a0[7] = (short)f2bf(wb0.w);
        a1[0] = (short)f2bf(wa1.x); a1[1] = (short)f2bf(wa1.y);
        a1[2] = (short)f2bf(wa1.z); a1[3] = (short)f2bf(wa1.w);
        a1[4] = (short)f2bf(wb1.x); a1[5] = (short)f2bf(wb1.y);
        a1[6] = (short)f2bf(wb1.z); a1[7] = (short)f2bf(wb1.w);
        #pragma unroll
        for (int t = 0; t < 4; ++t) {
            bf16x8 bt = *(const bf16x8*)(&xs[t * 16 + l16][lq * 8 + kk * 32]);
            acc[0][t] = __builtin_amdgcn_mfma_f32_16x16x32_bf16(a0, bt,
                                                                acc[0][t], 0, 0, 0);
            acc[1][t] = __builtin_amdgcn_mfma_f32_16x16x32_bf16(a1, bt,
                                                                acc[1][t], 0, 0, 0);
        }
    }

    const float inv21 = 1.0f / 21.0f;
    const float* pb = pts + (size_t)b * C * N;
    float* ob = out + (size_t)b * C * N;
    #pragma unroll
    for (int oo = 0; oo < 2; ++oo) {
        float bias[4];
        #pragma unroll
        for (int r = 0; r < 4; ++r) {
            int o = w * 32 + oo * 16 + lq * 4 + r;
            bias[r] = bc[o] + 20.f * bg[o];
        }
        #pragma unroll
        for (int t = 0; t < 4; ++t) {
            int n = n0 + t * 16 + l16;
            #pragma unroll
            for (int r = 0; r < 4; ++r) {
                int o = w * 32 + oo * 16 + lq * 4 + r;
                ob[(size_t)o * N + n] =
                    (acc[oo][t][r] + bias[r]) * inv21 + pb[(size_t)o * N + n];
            }
        }
    }
}

// ---------------------------------------------------------------------------
extern "C" void kernel_launch(void* const* d_in, const int* in_sizes, int n_in,
                              void* d_out, int out_size, void* d_ws, size_t ws_size,
                              hipStream_t stream) {
    const float* xyz = (const float*)d_in[0];
    const float* pts = (const float*)d_in[1];
    const float* Wc  = (const float*)d_in[2];
    const float* bc  = (const float*)d_in[3];
    const float* Wg  = (const float*)d_in[4];
    const float* bg  = (const float*)d_in[5];
    float* out = (float*)d_out;

    u16* X = (u16*)d_ws;                              // B*N*C2 bf16 = 16 MB
    float4* cand = (float4*)((char*)d_ws +
                             (size_t)B * N * C2 * sizeof(u16));  // +512 KB

    k_transpose_lrelu<<<dim3(N / 32, C / 32, B), dim3(32, 8), 0, stream>>>(
        pts, X, xyz, cand);
    k_knn_gather<<<dim3(N / 64, B), dim3(256), 0, stream>>>(cand, X);
    k_gemm_mfma<<<dim3(512), dim3(256), 0, stream>>>(X, Wc, Wg, pts, bc, bg, out);
}

// Round 9
// 267.913 us; speedup vs baseline: 1.1621x; 1.1621x over previous
//
#include <hip/hip_runtime.h>

// Problem constants
#define B 8
#define N 4096
#define C 128
#define CL 128          // X row stride (lower-half features only)
#define KNN 21          // top-(K+1), drop nearest
#define CAP 22          // per-lane append buffer capacity (slots 0..21)

typedef unsigned long long u64;
typedef unsigned int u32;
typedef unsigned short u16;

typedef __attribute__((ext_vector_type(8))) short bf16x8;
typedef __attribute__((ext_vector_type(4))) float f32x4;

__device__ __forceinline__ float bf2f(u16 u) {
    return __uint_as_float(((u32)u) << 16);
}
__device__ __forceinline__ u16 f2bf(float f) {  // round-to-nearest-even
    u32 x = __float_as_uint(f);
    return (u16)((x + 0x7FFFu + ((x >> 16) & 1u)) >> 16);
}

// ---------------------------------------------------------------------------
// K1: transpose + leaky_relu: points (B,C,N) f32 -> X[b][n][c] (c<128) bf16,
// row stride CL=128 (upper half now lives only in the fused kernel's LDS).
// Also prepacks cand[b][m] = float4(x, y, z, sq_norm) once per point.
// ---------------------------------------------------------------------------
__global__ __launch_bounds__(256) void k_transpose_lrelu(
        const float* __restrict__ pts, u16* __restrict__ X,
        const float* __restrict__ xyz, float4* __restrict__ cand) {
    __shared__ u16 tile[32][33];
    int b  = blockIdx.z;
    int c0 = blockIdx.y * 32;
    int n0 = blockIdx.x * 32;
    int tx = threadIdx.x, ty = threadIdx.y;   // 32 x 8

    if (blockIdx.y == 0 && ty == 0) {         // prepack: 32 lanes, 32 points
        int n = n0 + tx;
        const float* xz = xyz + (size_t)b * 3 * N;
        float x = xz[n], y = xz[N + n], z = xz[2 * N + n];
        float sn = __fadd_rn(__fadd_rn(__fmul_rn(x, x), __fmul_rn(y, y)),
                             __fmul_rn(z, z));
        cand[(size_t)b * N + n] = make_float4(x, y, z, sn);
    }

    const float* src = pts + (size_t)b * C * N;
    #pragma unroll
    for (int i = 0; i < 32; i += 8) {
        float v = src[(size_t)(c0 + ty + i) * N + n0 + tx];
        if (v < 0.f) v = __fmul_rn(v, 0.01f);
        tile[ty + i][tx] = f2bf(v);
    }
    __syncthreads();
    u16* dst = X + (size_t)b * N * CL;
    #pragma unroll
    for (int i = 0; i < 32; i += 8) {
        dst[(size_t)(n0 + ty + i) * CL + (c0 + tx)] = tile[tx][ty + i];
    }
}

// ---------------------------------------------------------------------------
// K2 (FUSED): exact KNN + gather-sum + MFMA GEMM + epilogue, one block per
// (b, 64-query n-panel) -- identical grid to the old K3, so the GEMM panel
// depends only on THIS block's gather output + K1's X. Phases:
//  A: scan/compact BYTE-FOR-BYTE r3 (u32 sortable keys; 7 attempted scan/
//     compact variants all regressed -- core frozen).
//  B: 4-way merge -> win (as r3).
//  C: gather-sum writes bf16 pairs STRAIGHT INTO the xs LDS panel upper half
//     (no global X round-trip; the old 8MB WRITE_SIZE disappears), while all
//     threads also stage the lower half from K1's X (coalesced).
//  D: old-K3 MFMA body verbatim: 4 waves x 2 o-tiles, W-frags cvt'd with the
//     same f2bf, B-frags ds_read_b128 from xs[64][264]; same C/D map, same
//     epilogue rounding.
// LDS overlays: A: stg 18432 | kbuf 22528 | ibuf 11264 = 52224. B: mg[256][21]
// u64 @0 (43008). C/D: xs[64][264] u16 @0 (33792, mg dead). win static.
// ---------------------------------------------------------------------------
__global__ __launch_bounds__(256) void k_knn_gemm(
        const float4* __restrict__ cand, const u16* __restrict__ X,
        const float* __restrict__ Wc, const float* __restrict__ Wg,
        const float* __restrict__ pts, const float* __restrict__ bc,
        const float* __restrict__ bg, float* __restrict__ out) {
    __shared__ __align__(16) char lds[52224];
    float4* stg  = (float4*)lds;                      // [4][288]  18432 B
    u32*    kbuf = (u32*)(lds + 18432);               // [CAP][256] 22528 B
    u16*    ibuf = (u16*)(lds + 18432 + 22528);       // [CAP][256] 11264 B
    u64*    mg   = (u64*)lds;                         // [256][21]  (phase B)
    u16 (*xs)[264] = (u16(*)[264])lds;                // [64][264]  (phase C/D)
    __shared__ u16 win[64 * KNN];

    int tid = threadIdx.x;
    int w = tid >> 6, l = tid & 63;
    int b = blockIdx.y;
    int n0 = blockIdx.x * 64;
    int nq = n0 + l;

    const float4* candb = cand + (size_t)b * N;
    float4 cq = candb[nq];                            // query point (coalesced)
    float qx = cq.x, qy = cq.y, qz = cq.z, snq = cq.w;

    u32 key[KNN], idx[KNN];
    #pragma unroll
    for (int i = 0; i < KNN; ++i) { key[i] = 0xFFFFFFFFu; idx[i] = 0u; }
    int cnt = 0;
    u32 thr = 0xFFFFFFFFu;

    auto compact = [&]() {
        #pragma unroll 1
        for (int i = 0; i < CAP; ++i) {
            if (__ballot(i < cnt) == 0ull) break;
            u32 kv = kbuf[i * 256 + tid];
            u32 iv = ibuf[i * 256 + tid];
            bool ins = (i < cnt) && (kv < key[20]);   // strict: ties keep old
            if (__ballot(ins) != 0ull) {
                key[20] = ins ? kv : key[20];
                idx[20] = ins ? iv : idx[20];
                #pragma unroll
                for (int t = 19; t >= 0; --t) {       // stable bubble (strict >)
                    bool sw = key[t] > key[t + 1];
                    u32 ka = sw ? key[t + 1] : key[t];
                    u32 kz = sw ? key[t] : key[t + 1];
                    u32 ia = sw ? idx[t + 1] : idx[t];
                    u32 iz = sw ? idx[t] : idx[t + 1];
                    key[t] = ka; key[t + 1] = kz;
                    idx[t] = ia; idx[t + 1] = iz;
                }
            }
        }
        cnt = 0;
        thr = key[20];
    };

    float4* mystg = stg + w * 288;
    int wl = l + (l >> 3);                            // padded staging index

    for (int sc = 0; sc < 4; ++sc) {
        int m0 = w * 1024 + sc * 256;
        // stage 256 candidates from prepacked cand (coalesced float4)
        float4 v0 = candb[m0 + l];
        float4 v1 = candb[m0 + l + 64];
        float4 v2 = candb[m0 + l + 128];
        float4 v3 = candb[m0 + l + 192];
        mystg[wl]       = v0;                         // conflict-free writes
        mystg[wl + 72]  = v1;
        mystg[wl + 144] = v2;
        mystg[wl + 216] = v3;
        asm volatile("s_waitcnt lgkmcnt(0)" ::: "memory");
        for (int cc = 0; cc < 256; cc += 8) {
            int base = cc + (cc >> 3);                // wave-uniform padded base
            #pragma unroll
            for (int j = 0; j < 8; ++j) {
                float4 cp = mystg[base + j];          // wave-broadcast read
                int m = m0 + cc + j;
                float dot = __fadd_rn(__fadd_rn(__fmul_rn(qx, cp.x),
                                                __fmul_rn(qy, cp.y)),
                                      __fmul_rn(qz, cp.z));
                float sq = __fadd_rn(__fsub_rn(snq, __fadd_rn(dot, dot)), cp.w);
                u32 bits = __float_as_uint(sq);
                u32 kb = bits ^ (0x80000000u | (u32)(((int)bits) >> 31));
                kbuf[cnt * 256 + tid] = kb;           // unconditional append
                ibuf[cnt * 256 + tid] = (u16)m;
                cnt += (kb < thr);                    // strict: ties dropped
            }
            if (__ballot(cnt >= 15) != 0ull) compact();
        }
    }
    compact();

    __syncthreads();                                  // phase-A buffers dead
    #pragma unroll
    for (int j = 0; j < KNN; ++j)
        mg[(w * 64 + l) * KNN + j] = ((u64)key[j] << 32) | (u64)idx[j];
    __syncthreads();

    if (w == 0) {                                     // 4-way merge per query
        int p0 = 0, p1 = 0, p2 = 0, p3 = 0;
        for (int j = 0; j < KNN; ++j) {
            u64 c0 = mg[(0 * 64 + l) * KNN + p0];
            u64 c1 = mg[(1 * 64 + l) * KNN + p1];
            u64 c2 = mg[(2 * 64 + l) * KNN + p2];
            u64 c3 = mg[(3 * 64 + l) * KNN + p3];
            u64 m01 = c0 < c1 ? c0 : c1; int s01 = c0 < c1 ? 0 : 1;
            u64 m23 = c2 < c3 ? c2 : c3; int s23 = c2 < c3 ? 2 : 3;
            u64 mm = m01 < m23 ? m01 : m23;
            int sel = m01 < m23 ? s01 : s23;
            win[l * KNN + j] = (u16)(mm & 0xFFFFu);
            p0 += (sel == 0); p1 += (sel == 1); p2 += (sel == 2); p3 += (sel == 3);
        }
    }
    __syncthreads();                                  // win ready; mg dead

    // ---- phase C: stage xs lower half (coalesced) + gather-sum into upper
    const u16* Xb = X + (size_t)b * N * CL;
    #pragma unroll
    for (int it = 0; it < 4; ++it) {                  // 64 rows x 16 chunks
        int t = it * 256 + tid;                       // 0..1023
        int r = t >> 4, cch = t & 15;                 // row, 16B chunk
        *(bf16x8*)(&xs[r][cch * 8]) =
            *(const bf16x8*)(Xb + (size_t)(n0 + r) * CL + cch * 8);
    }
    for (int qq = 0; qq < 16; ++qq) {                 // wave w: 16 queries
        int q = w * 16 + qq;
        float f0 = 0.f, f1 = 0.f;
        #pragma unroll
        for (int j = 1; j < KNN; ++j) {               // skip nearest (j=0)
            int m = win[q * KNN + j];
            u32 u2 = *(const u32*)(Xb + (size_t)m * CL + 2 * l);
            f0 += bf2f((u16)(u2 & 0xFFFFu));
            f1 += bf2f((u16)(u2 >> 16));
        }
        *(u32*)(&xs[q][128 + 2 * l]) =                // straight into LDS
            ((u32)f2bf(f1) << 16) | (u32)f2bf(f0);
    }
    __syncthreads();                                  // xs panel complete

    // ---- phase D: old-K3 MFMA body (wave w -> o rows w*32..w*32+31)
    int lane = tid & 63;
    int l16 = lane & 15, lq = lane >> 4;
    const float* wc0 = Wc + (size_t)(w * 32 + l16) * 128 + lq * 8;
    const float* wc1 = Wc + (size_t)(w * 32 + 16 + l16) * 128 + lq * 8;
    const float* wg0 = Wg + (size_t)(w * 32 + l16) * 128 + lq * 8;
    const float* wg1 = Wg + (size_t)(w * 32 + 16 + l16) * 128 + lq * 8;

    f32x4 acc[2][4];
    #pragma unroll
    for (int oo = 0; oo < 2; ++oo)
        #pragma unroll
        for (int t = 0; t < 4; ++t)
            acc[oo][t] = (f32x4){0.f, 0.f, 0.f, 0.f};

    #pragma unroll
    for (int kk = 0; kk < 8; ++kk) {
        const float* s0 = (kk < 4) ? (wc0 + kk * 32) : (wg0 + (kk - 4) * 32);
        const float* s1 = (kk < 4) ? (wc1 + kk * 32) : (wg1 + (kk - 4) * 32);
        float4 wa0 = *(const float4*)s0, wb0 = *(const float4*)(s0 + 4);
        float4 wa1 = *(const float4*)s1, wb1 = *(const float4*)(s1 + 4);
        bf16x8 a0, a1;
        a0[0] = (short)f2bf(wa0.x); a0[1] = (short)f2bf(wa0.y);
        a0[2] = (short)f2bf(wa0.z); a0[3] = (short)f2bf(wa0.w);
        a0[4] = (short)f2bf(wb0.x); a0[5] = (short)f2bf(wb0.y);
        a0[6] = (short)f2bf(wb0.z); a0[7] = (short)f2bf(wb0.w);
        a1[0] = (short)f2bf(wa1.x); a1[1] = (short)f2bf(wa1.y);
        a1[2] = (short)f2bf(wa1.z); a1[3] = (short)f2bf(wa1.w);
        a1[4] = (short)f2bf(wb1.x); a1[5] = (short)f2bf(wb1.y);
        a1[6] = (short)f2bf(wb1.z); a1[7] = (short)f2bf(wb1.w);
        #pragma unroll
        for (int t = 0; t < 4; ++t) {
            bf16x8 bt = *(const bf16x8*)(&xs[t * 16 + l16][lq * 8 + kk * 32]);
            acc[0][t] = __builtin_amdgcn_mfma_f32_16x16x32_bf16(a0, bt,
                                                                acc[0][t], 0, 0, 0);
            acc[1][t] = __builtin_amdgcn_mfma_f32_16x16x32_bf16(a1, bt,
                                                                acc[1][t], 0, 0, 0);
        }
    }

    const float inv21 = 1.0f / 21.0f;
    const float* pb = pts + (size_t)b * C * N;
    float* ob = out + (size_t)b * C * N;
    #pragma unroll
    for (int oo = 0; oo < 2; ++oo) {
        float bias[4];
        #pragma unroll
        for (int r = 0; r < 4; ++r) {
            int o = w * 32 + oo * 16 + lq * 4 + r;
            bias[r] = bc[o] + 20.f * bg[o];
        }
        #pragma unroll
        for (int t = 0; t < 4; ++t) {
            int n = n0 + t * 16 + l16;
            #pragma unroll
            for (int r = 0; r < 4; ++r) {
                int o = w * 32 + oo * 16 + lq * 4 + r;
                ob[(size_t)o * N + n] =
                    (acc[oo][t][r] + bias[r]) * inv21 + pb[(size_t)o * N + n];
            }
        }
    }
}

// ---------------------------------------------------------------------------
extern "C" void kernel_launch(void* const* d_in, const int* in_sizes, int n_in,
                              void* d_out, int out_size, void* d_ws, size_t ws_size,
                              hipStream_t stream) {
    const float* xyz = (const float*)d_in[0];
    const float* pts = (const float*)d_in[1];
    const float* Wc  = (const float*)d_in[2];
    const float* bc  = (const float*)d_in[3];
    const float* Wg  = (const float*)d_in[4];
    const float* bg  = (const float*)d_in[5];
    float* out = (float*)d_out;

    u16* X = (u16*)d_ws;                              // B*N*CL bf16 = 8 MB
    float4* cand = (float4*)((char*)d_ws +
                             (size_t)B * N * CL * sizeof(u16));  // +512 KB

    k_transpose_lrelu<<<dim3(N / 32, C / 32, B), dim3(32, 8), 0, stream>>>(
        pts, X, xyz, cand);
    k_knn_gemm<<<dim3(N / 64, B), dim3(256), 0, stream>>>(
        cand, X, Wc, Wg, pts, bc, bg, out);
}